// Round 19
// baseline (108.222 us; speedup 1.0000x reference)
//
#include <hip/hip_runtime.h>
#include <math.h>

#if defined(__has_include)
#if __has_include(<hip/hip_bf16.h>)
#include <hip/hip_bf16.h>
#define HAVE_BF16_H 1
#endif
#endif

#define CIN    64
#define OUTC   64
#define BOT    16
#define KK     9
#define HH     48
#define WW     48
#define LPIX   (HH*WW)
#define WSZ    9216
#define PSZ    1024
#define PREDCH 10304
#define GRPSZ  2576
#define BATCH  2
#define NPX    18          // 3 rows x 6 cols of pixels per block
#define PXS2   1172        // px-stride (ushorts): 64*18 + 20 pad (conflict-free)
#define QS2    1160        // Q px-stride (ushorts): 64*18 + 8 pad
#define DBS    65

typedef __attribute__((ext_vector_type(8))) short short8v;
typedef __attribute__((ext_vector_type(4))) short short4v;
typedef __attribute__((ext_vector_type(4))) float float4v;
typedef __attribute__((ext_vector_type(2))) float float2v;

__device__ inline unsigned short f2bf(float f){
    unsigned u = __float_as_uint(f);
    return (unsigned short)((u + 0x7FFFu + ((u>>16)&1u)) >> 16);   // RNE
}

// Packed f32x2 -> bf16x2 (low = lo).  Native path lowers to
// v_cvt_pk_bf16_f32 (RNE, bit-identical to f2bf).  No inline asm (R6).
__device__ inline unsigned pk2bf(float lo, float hi){
#ifdef HAVE_BF16_H
    __hip_bfloat162 t = __float22bfloat162_rn(float2{lo, hi});
    unsigned r; __builtin_memcpy(&r, &t, 4); return r;
#else
    return (unsigned)f2bf(lo) | ((unsigned)f2bf(hi) << 16);
#endif
}

// K=16 bf16 MFMA (2-VGPR operands; lane: row=lane&15, k=quad*4+i).
// Verified numerically in R14-R18.  Fallback zero-extends to K=32.
#if __has_builtin(__builtin_amdgcn_mfma_f32_16x16x16bf16_1k)
__device__ __forceinline__ float4v ymfma(short4v a, short4v b, float4v c) {
    return __builtin_amdgcn_mfma_f32_16x16x16bf16_1k(a, b, c, 0, 0, 0);
}
#else
__device__ __forceinline__ float4v ymfma(short4v a, short4v b, float4v c) {
    short8v a8 = {a[0], a[1], a[2], a[3], 0, 0, 0, 0};
    short8v b8 = {b[0], b[1], b[2], b[3], 0, 0, 0, 0};
    return __builtin_amdgcn_mfma_f32_16x16x32_bf16(a8, b8, c, 0, 0, 0);
}
#endif

__global__ __launch_bounds__(256) void cvt_wp(const float* __restrict__ Wp,
                                              unsigned short* __restrict__ Wb) {
    const int n = PREDCH * 16;
    for (int i = blockIdx.x * 256 + threadIdx.x; i < n; i += gridDim.x * 256)
        Wb[i] = f2bf(Wp[i]);
}

// Block = 18 px (3x6), grid 256 (1/CU), 1024 threads (16 waves).
// vs dppc25 (R18, profiled 47.2us champion): TAP BODY REORDER (pure
// program-order change, zero register cost).  A wave's DS ops process in
// issue order; the old body {PRED(t+1) -> PREFETCH(t+2) -> Y(t)} enqueued
// ~16 ds_writes to S before Y's 8 ds_reads (also from S) could issue, so
// Y's reads -- whose data has been ready since the PREVIOUS barrier --
// queued behind the full store stream.  New body: {Y(t) -> PRED(t+1) ->
// PREFETCH(t+2) -> barrier}: Y's reads issue first and feed its
// MFMA/reduce chain immediately; PRED's MFMAs (register inputs) fill the
// gaps; PRED stores drain at the barrier; PREFETCH Wb loads get a full
// barrier+Y of slack.  Y reads S[buf], PRED writes S[buf^1] -- disjoint,
// order-invariant.  Everything else R18-verbatim.
__global__ __launch_bounds__(1024) __attribute__((amdgpu_waves_per_eu(4, 4)))
void dppc26(
    const float* __restrict__ x,
    const unsigned short* __restrict__ Wb,
    const float* __restrict__ bp,
    float* __restrict__ out)
{
    __shared__ float          xt[64 * 5 * 8];       // 10240 B  [c][r5][c8]
    __shared__ float          xtT[5 * 8 * 64];      // 10240 B  [r5*8+c8][c]
    __shared__ unsigned short S[2][NPX * PXS2];     // 84384 B  P_t dbuf
    __shared__ unsigned short Qs[NPX * QS2];        // 41760 B  Q [px][o*18+d]
    __shared__ unsigned short Bfs[4 * 2 * 64 * 4];  //  4096 B  pred B-frags [g][nt][lane][4]
    __shared__ float          dynb[NPX * DBS];      //  4680 B

    const int tid  = threadIdx.x;
    const int wave = tid >> 6;
    const int lane = tid & 63;
    const int quad = lane >> 4;
    const int lrow = lane & 15;

    const int bi = blockIdx.x;
    const int b  = bi >> 7;
    const int r  = bi & 127;
    const int h0 = (r >> 3) * 3;
    const int w0 = (r & 7) * 6;

    // ---- xt load (coalesced global) ----
    const float* xb = x + (size_t)b * CIN * LPIX;
    for (int i = tid; i < 64 * 5 * 8; i += 1024) {
        const int c  = i / 40;
        const int rm = i - c * 40;
        const int hi = h0 - 1 + (rm >> 3);
        const int wi = w0 - 1 + (rm & 7);
        float v = 0.0f;
        if (hi >= 0 && hi < HH && wi >= 0 && wi < WW)
            v = xb[c * LPIX + hi * WW + wi];
        xt[i] = v;
    }
    __syncthreads();

    // ---- waves 0-7: pred B-frags -> LDS (K=16 layout: c = g*16+quad*4+i) ----
    if (wave < 8) {
        const int g  = wave >> 1;
        const int nt = wave & 1;
        const int px = nt * 16 + lrow;
        unsigned fw[2] = {0u, 0u};
        if (px < NPX) {
            const int pr = px / 6, pc = px - 6 * (px / 6);
            #pragma unroll
            for (int jj = 0; jj < 2; ++jj) {
                const float x0 = xt[((g * 16 + quad * 4 + 2 * jj)     * 5 + pr + 1) * 8 + pc + 1];
                const float x1 = xt[((g * 16 + quad * 4 + 2 * jj + 1) * 5 + pr + 1) * 8 + pc + 1];
                fw[jj] = pk2bf(x0, x1);
            }
        }
        unsigned* bq = (unsigned*)&Bfs[((g * 2 + nt) * 64 + lane) * 4];
        bq[0] = fw[0]; bq[1] = fw[1];
    } else {
        // ---- waves 8-15: transpose xt -> xtT[spatial][c] (for pv b128 reads) ----
        for (int i = tid - 512; i < 64 * 5 * 8; i += 512) {
            const int sp = i >> 6;
            const int c  = i & 63;
            xtT[i] = xt[c * 40 + sp];
        }
    }
    __syncthreads();

    // ---- Q + dyn_b phase (group 3), K=16, bias via C operand ----
    for (int u = wave; u < 68; u += 16) {
        const int ch0  = WSZ + u * 16;
        const int mych = ch0 + lrow;
        const short4v a = *(const short4v*)(Wb + (size_t)mych * 16 + quad * 4);
        float4v Cb;
        #pragma unroll
        for (int rr = 0; rr < 4; ++rr) Cb[rr] = bp[ch0 + quad * 4 + rr];
        #pragma unroll
        for (int nt = 0; nt < 2; ++nt) {
            const short4v bfr = *(const short4v*)&Bfs[((3 * 2 + nt) * 64 + lane) * 4];
            const float4v Dv = ymfma(a, bfr, Cb);
            const int px = nt * 16 + lrow;
            if (px < NPX) {
                if (u < 64) {   // proj region: 4 consecutive ushorts, packed b32
                    unsigned short* p = &Qs[px * QS2 + u * 18 + quad * 4];
                    *(unsigned int*)(p)     = pk2bf(Dv[0], Dv[1]);
                    *(unsigned int*)(p + 2) = pk2bf(Dv[2], Dv[3]);
                } else {        // dyn_b region
                    #pragma unroll
                    for (int rr = 0; rr < 4; ++rr)
                        dynb[px * DBS + (u - 64) * 16 + quad * 4 + rr] = Dv[rr];
                }
            }
        }
    }

    // ---- PRED geometry (u&15 == wave): c0 = 4*wave invariant; d0 = 4*uu ----
    const int c0    = wave * 4;
    const int mybase = (lrow & 3) * 576 + (lrow >> 2) * 9;   // row-remap offset

    // ---- cross-tap A-fragment prefetch: FULL depth, K=16 (8 VGPRs) ----
    short4v apre[4];

    #define PRED_PREFETCH(T)                                                          \
    _Pragma("unroll")                                                                 \
    for (int uu = 0; uu < 4; ++uu) {                                                  \
        const int mych = uu * 2304 + c0 * 9 + (T) + mybase;                           \
        apre[uu] = *(const short4v*)(Wb + (size_t)mych * 16 + quad * 4);              \
    }

    // ---- pred slice for tap t into buf (K=16 MFMA, bias via C) ----
    // Row remap: A-row lrow -> channel chmin + (lrow&3)*576 + (lrow>>2)*9,
    // so Dv[rr] = (d=d0+rr, c=c0+quad); bias channel = chmin + rr*576 + quad*9.
    #define PASS(GG, NT)                                                              \
        { short4v am = (myg == (GG)) ? a : (short4v)0;                                \
          const short4v bfr = *(const short4v*)&Bfs[(((GG) * 2 + (NT)) * 64 + lane) * 4]; \
          Dv = ymfma(am, bfr, Dv); }

    #define PRED_BODY(T, BUF)                                                         \
        const int g0  = chmin / GRPSZ;                                                \
        const int g1  = (chmin + 1755) / GRPSZ;                                       \
        const int myg = (chmin + mybase) / GRPSZ;                                     \
        float4v Cb;                                                                   \
        _Pragma("unroll")                                                             \
        for (int rr = 0; rr < 4; ++rr) Cb[rr] = bp[chmin + rr * 576 + quad * 9];      \
        _Pragma("unroll")                                                             \
        for (int nt = 0; nt < 2; ++nt) {                                              \
            float4v Dv = Cb;                                                          \
            if (g0 == 0)      { PASS(0, nt) if (g1 == 1) PASS(1, nt) }                \
            else if (g0 == 1) { PASS(1, nt) if (g1 == 2) PASS(2, nt) }                \
            else if (g0 == 2) { PASS(2, nt) if (g1 == 3) PASS(3, nt) }                \
            else              { PASS(3, nt) }                                         \
            const int px = nt * 16 + lrow;                                            \
            if (px < NPX) {                                                           \
                unsigned short* p = &S[BUF][px * PXS2 + (c0 + quad) * 18 + uu * 4];   \
                *(unsigned int*)(p)     = pk2bf(Dv[0], Dv[1]);                        \
                *(unsigned int*)(p + 2) = pk2bf(Dv[2], Dv[3]);                        \
            }                                                                         \
        }

    // tap-0 PRED: inline loads (prologue, nothing to prefetch from)
    #define PRED_SLICE0(T, BUF)                                                       \
    _Pragma("unroll")                                                                 \
    for (int uu = 0; uu < 4; ++uu) {                                                  \
        const int chmin = uu * 2304 + c0 * 9 + (T);                                   \
        const int mych  = chmin + mybase;                                             \
        const short4v a = *(const short4v*)(Wb + (size_t)mych * 16 + quad * 4);       \
        PRED_BODY(T, BUF)                                                             \
    }

    // steady-state PRED: all 4 uu consume apre (prefetched one tap earlier)
    #define PRED_COMPUTE(T, BUF)                                                      \
    _Pragma("unroll")                                                                 \
    for (int uu = 0; uu < 4; ++uu) {                                                  \
        const int chmin = uu * 2304 + c0 * 9 + (T);                                   \
        const short4v a = apre[uu];                                                   \
        PRED_BODY(T, BUF)                                                             \
    }

    PRED_SLICE0(0, 0)
    PRED_PREFETCH(1)
    __syncthreads();   // covers Qs, dynb, S[0]

    // ---- Y-task assignment: 72 (px,Nt) tasks over 16 waves ----
    const int ntask  = (wave < 8) ? 5 : 4;
    const int tstart = (wave < 8) ? 5 * wave : 40 + 4 * (wave - 8);
    float acc[5] = {0.f, 0.f, 0.f, 0.f, 0.f};

    // ---- hoist tap-invariant Q fragments: one b64 load per task, ONCE ----
    short4v Bq[5];
    #pragma unroll
    for (int k = 0; k < 5; ++k) {
        if (k < ntask) {
            const int tau = tstart + k;
            const int px  = tau >> 2;
            const int Nt  = tau & 3;
            Bq[k] = *(const short4v*)&Qs[px * QS2 + (Nt * 16 + lrow) * 18 + quad * 4];
        } else {
            Bq[k] = (short4v)0;
        }
    }

    for (int t = 0; t < KK; ++t) {
        const int buf = t & 1;
        const int tr = t / 3, tc = t - 3 * (t / 3);

        // ---- Y(t) FIRST: its S[buf] reads have been ready since the last
        //      barrier; issuing them before PRED's store stream keeps them
        //      at the head of the DS queue ----
        int lastpx = -1;
        short4v Ap[4];                      // K=16 fragments: 2 VGPRs each
        float4v pv4[4];
        #pragma unroll
        for (int k = 0; k < 5; ++k) {
            if (k < ntask) {
                const int tau = tstart + k;
                const int px  = tau >> 2;
                const int pr = px / 6, pc = px - 6 * (px / 6);

                if (px != lastpx) {          // wave-uniform branch
                    lastpx = px;
                    #pragma unroll
                    for (int Mt = 0; Mt < 4; ++Mt)   // all 64 lanes load (k=quad*4+i)
                        Ap[Mt] = *(const short4v*)&S[buf][px * PXS2 + (Mt * 16 + lrow) * 18 + quad * 4];
                    const int spb = ((pr + tr) * 8 + pc + tc) * 64;
                    #pragma unroll
                    for (int Mt = 0; Mt < 4; ++Mt)
                        pv4[Mt] = *(const float4v*)&xtT[spb + Mt * 16 + quad * 4];
                }

                // packed f32x2 reduction (v_pk_fma_f32)
                float2v n2 = {0.f, 0.f}, d2 = {0.f, 0.f};
                #pragma unroll
                for (int Mt = 0; Mt < 4; ++Mt) {
                    float4v Dv = {0.f, 0.f, 0.f, 0.f};
                    Dv = ymfma(Ap[Mt], Bq[k], Dv);
                    const float2v y0 = {Dv[0], Dv[1]},        y1 = {Dv[2], Dv[3]};
                    const float2v p0 = {pv4[Mt][0], pv4[Mt][1]}, p1 = {pv4[Mt][2], pv4[Mt][3]};
                    n2 = y0 * y0 + n2;  n2 = y1 * y1 + n2;
                    d2 = p0 * y0 + d2;  d2 = p1 * y1 + d2;
                }
                float nacc  = n2[0] + n2[1];
                float dpacc = d2[0] + d2[1];
                nacc  += __shfl_xor(nacc, 16);  nacc  += __shfl_xor(nacc, 32);
                dpacc += __shfl_xor(dpacc, 16); dpacc += __shfl_xor(dpacc, 32);
                acc[k] += dpacc * rsqrtf(fmaxf(nacc, 1e-24f));
            }
        }

        // ---- then PRED(t+1) (writes S[buf^1], register-input MFMAs) and
        //      PREFETCH(t+2) (global loads with a full barrier+Y of slack) ----
        if (t < 8) { PRED_COMPUTE(t + 1, (t + 1) & 1) }
        if (t < 7) { PRED_PREFETCH(t + 2) }

        __syncthreads();
    }

    // ---- write out ----
    if (quad == 0) {
        #pragma unroll
        for (int k = 0; k < 5; ++k) {
            if (k < ntask) {
                const int tau = tstart + k;
                const int px  = tau >> 2;
                const int Nt  = tau & 3;
                const int pr = px / 6, pc = px - 6 * (px / 6);
                const int l  = (h0 + pr) * WW + (w0 + pc);
                const int o  = Nt * 16 + lrow;
                out[((size_t)b * OUTC + o) * LPIX + l] = acc[k] + dynb[px * DBS + o];
            }
        }
    }
}

extern "C" void kernel_launch(void* const* d_in, const int* in_sizes, int n_in,
                              void* d_out, int out_size, void* d_ws, size_t ws_size,
                              hipStream_t stream) {
    const float* x  = (const float*)d_in[0];
    const float* Wp = (const float*)d_in[1];
    const float* bp = (const float*)d_in[2];
    float* out = (float*)d_out;
    unsigned short* Wb = (unsigned short*)d_ws;   // PREDCH*16 bf16 = 330 KB
    (void)in_sizes; (void)n_in; (void)out_size; (void)ws_size;

    hipLaunchKernelGGL(cvt_wp, dim3(160), dim3(256), 0, stream, Wp, Wb);
    hipLaunchKernelGGL(dppc26, dim3(BATCH * 128), dim3(1024), 0, stream, x, Wb, bp, out);
}

// Round 20
// 106.582 us; speedup vs baseline: 1.0154x; 1.0154x over previous
//
#include <hip/hip_runtime.h>
#include <math.h>

#if defined(__has_include)
#if __has_include(<hip/hip_bf16.h>)
#include <hip/hip_bf16.h>
#define HAVE_BF16_H 1
#endif
#endif

#define CIN    64
#define OUTC   64
#define BOT    16
#define KK     9
#define HH     48
#define WW     48
#define LPIX   (HH*WW)
#define WSZ    9216
#define PSZ    1024
#define PREDCH 10304
#define GRPSZ  2576
#define BATCH  2
#define NPX    18          // 3 rows x 6 cols of pixels per block
#define PXS2   1172        // px-stride (ushorts): 64*18 + 20 pad (conflict-free)
#define QS2    1160        // Q px-stride (ushorts): 64*18 + 8 pad
#define DBS    65

typedef __attribute__((ext_vector_type(8))) short short8v;
typedef __attribute__((ext_vector_type(4))) short short4v;
typedef __attribute__((ext_vector_type(4))) float float4v;
typedef __attribute__((ext_vector_type(2))) float float2v;

__device__ inline unsigned short f2bf(float f){
    unsigned u = __float_as_uint(f);
    return (unsigned short)((u + 0x7FFFu + ((u>>16)&1u)) >> 16);   // RNE
}

// Packed f32x2 -> bf16x2 (low = lo).  Native path lowers to
// v_cvt_pk_bf16_f32 (RNE, bit-identical to f2bf).  No inline asm (R6).
__device__ inline unsigned pk2bf(float lo, float hi){
#ifdef HAVE_BF16_H
    __hip_bfloat162 t = __float22bfloat162_rn(float2{lo, hi});
    unsigned r; __builtin_memcpy(&r, &t, 4); return r;
#else
    return (unsigned)f2bf(lo) | ((unsigned)f2bf(hi) << 16);
#endif
}

// K=16 bf16 MFMA (2-VGPR operands; lane: row=lane&15, k=quad*4+i).
// Verified numerically in R14-R18.  Fallback zero-extends to K=32.
#if __has_builtin(__builtin_amdgcn_mfma_f32_16x16x16bf16_1k)
__device__ __forceinline__ float4v ymfma(short4v a, short4v b, float4v c) {
    return __builtin_amdgcn_mfma_f32_16x16x16bf16_1k(a, b, c, 0, 0, 0);
}
#else
__device__ __forceinline__ float4v ymfma(short4v a, short4v b, float4v c) {
    short8v a8 = {a[0], a[1], a[2], a[3], 0, 0, 0, 0};
    short8v b8 = {b[0], b[1], b[2], b[3], 0, 0, 0, 0};
    return __builtin_amdgcn_mfma_f32_16x16x32_bf16(a8, b8, c, 0, 0, 0);
}
#endif

__global__ __launch_bounds__(256) void cvt_wp(const float* __restrict__ Wp,
                                              unsigned short* __restrict__ Wb) {
    const int n = PREDCH * 16;
    for (int i = blockIdx.x * 256 + threadIdx.x; i < n; i += gridDim.x * 256)
        Wb[i] = f2bf(Wp[i]);
}

// Block = 18 px (3x6), grid 256 (1/CU), 1024 threads (16 waves).
// vs dppc26 (R19, 55.2us REGRESSION -- Y-first starved PREFETCH of issue
// slack: VALUBusy fell 37.6->32.4, pure added stall): REVERT to dppc25's
// (R18, 47.2us champion) tap order {PRED(t+1) -> PREFETCH(t+2) -> Y(t) ->
// barrier}, plus one strictly-slack-increasing refinement: PREFETCH is
// FUSED into PRED_COMPUTE -- apre[uu] is re-loaded for tap t+2 immediately
// after its tap-t+1 value is consumed (per-uu), instead of after all four
// PRED bodies.  Each Wb load gains up to 3 PRED-body-lengths of extra
// slack; destination register provably free; register count unchanged.
__global__ __launch_bounds__(1024) __attribute__((amdgpu_waves_per_eu(4, 4)))
void dppc27(
    const float* __restrict__ x,
    const unsigned short* __restrict__ Wb,
    const float* __restrict__ bp,
    float* __restrict__ out)
{
    __shared__ float          xt[64 * 5 * 8];       // 10240 B  [c][r5][c8]
    __shared__ float          xtT[5 * 8 * 64];      // 10240 B  [r5*8+c8][c]
    __shared__ unsigned short S[2][NPX * PXS2];     // 84384 B  P_t dbuf
    __shared__ unsigned short Qs[NPX * QS2];        // 41760 B  Q [px][o*18+d]
    __shared__ unsigned short Bfs[4 * 2 * 64 * 4];  //  4096 B  pred B-frags [g][nt][lane][4]
    __shared__ float          dynb[NPX * DBS];      //  4680 B

    const int tid  = threadIdx.x;
    const int wave = tid >> 6;
    const int lane = tid & 63;
    const int quad = lane >> 4;
    const int lrow = lane & 15;

    const int bi = blockIdx.x;
    const int b  = bi >> 7;
    const int r  = bi & 127;
    const int h0 = (r >> 3) * 3;
    const int w0 = (r & 7) * 6;

    // ---- xt load (coalesced global) ----
    const float* xb = x + (size_t)b * CIN * LPIX;
    for (int i = tid; i < 64 * 5 * 8; i += 1024) {
        const int c  = i / 40;
        const int rm = i - c * 40;
        const int hi = h0 - 1 + (rm >> 3);
        const int wi = w0 - 1 + (rm & 7);
        float v = 0.0f;
        if (hi >= 0 && hi < HH && wi >= 0 && wi < WW)
            v = xb[c * LPIX + hi * WW + wi];
        xt[i] = v;
    }
    __syncthreads();

    // ---- waves 0-7: pred B-frags -> LDS (K=16 layout: c = g*16+quad*4+i) ----
    if (wave < 8) {
        const int g  = wave >> 1;
        const int nt = wave & 1;
        const int px = nt * 16 + lrow;
        unsigned fw[2] = {0u, 0u};
        if (px < NPX) {
            const int pr = px / 6, pc = px - 6 * (px / 6);
            #pragma unroll
            for (int jj = 0; jj < 2; ++jj) {
                const float x0 = xt[((g * 16 + quad * 4 + 2 * jj)     * 5 + pr + 1) * 8 + pc + 1];
                const float x1 = xt[((g * 16 + quad * 4 + 2 * jj + 1) * 5 + pr + 1) * 8 + pc + 1];
                fw[jj] = pk2bf(x0, x1);
            }
        }
        unsigned* bq = (unsigned*)&Bfs[((g * 2 + nt) * 64 + lane) * 4];
        bq[0] = fw[0]; bq[1] = fw[1];
    } else {
        // ---- waves 8-15: transpose xt -> xtT[spatial][c] (for pv b128 reads) ----
        for (int i = tid - 512; i < 64 * 5 * 8; i += 512) {
            const int sp = i >> 6;
            const int c  = i & 63;
            xtT[i] = xt[c * 40 + sp];
        }
    }
    __syncthreads();

    // ---- Q + dyn_b phase (group 3), K=16, bias via C operand ----
    for (int u = wave; u < 68; u += 16) {
        const int ch0  = WSZ + u * 16;
        const int mych = ch0 + lrow;
        const short4v a = *(const short4v*)(Wb + (size_t)mych * 16 + quad * 4);
        float4v Cb;
        #pragma unroll
        for (int rr = 0; rr < 4; ++rr) Cb[rr] = bp[ch0 + quad * 4 + rr];
        #pragma unroll
        for (int nt = 0; nt < 2; ++nt) {
            const short4v bfr = *(const short4v*)&Bfs[((3 * 2 + nt) * 64 + lane) * 4];
            const float4v Dv = ymfma(a, bfr, Cb);
            const int px = nt * 16 + lrow;
            if (px < NPX) {
                if (u < 64) {   // proj region: 4 consecutive ushorts, packed b32
                    unsigned short* p = &Qs[px * QS2 + u * 18 + quad * 4];
                    *(unsigned int*)(p)     = pk2bf(Dv[0], Dv[1]);
                    *(unsigned int*)(p + 2) = pk2bf(Dv[2], Dv[3]);
                } else {        // dyn_b region
                    #pragma unroll
                    for (int rr = 0; rr < 4; ++rr)
                        dynb[px * DBS + (u - 64) * 16 + quad * 4 + rr] = Dv[rr];
                }
            }
        }
    }

    // ---- PRED geometry (u&15 == wave): c0 = 4*wave invariant; d0 = 4*uu ----
    const int c0    = wave * 4;
    const int mybase = (lrow & 3) * 576 + (lrow >> 2) * 9;   // row-remap offset

    // ---- cross-tap A-fragment prefetch: FULL depth, K=16 (8 VGPRs) ----
    short4v apre[4];

    #define PRED_PREFETCH(T)                                                          \
    _Pragma("unroll")                                                                 \
    for (int uu = 0; uu < 4; ++uu) {                                                  \
        const int mych = uu * 2304 + c0 * 9 + (T) + mybase;                           \
        apre[uu] = *(const short4v*)(Wb + (size_t)mych * 16 + quad * 4);              \
    }

    // ---- pred slice for tap t into buf (K=16 MFMA, bias via C) ----
    // Row remap: A-row lrow -> channel chmin + (lrow&3)*576 + (lrow>>2)*9,
    // so Dv[rr] = (d=d0+rr, c=c0+quad); bias channel = chmin + rr*576 + quad*9.
    #define PASS(GG, NT)                                                              \
        { short4v am = (myg == (GG)) ? a : (short4v)0;                                \
          const short4v bfr = *(const short4v*)&Bfs[(((GG) * 2 + (NT)) * 64 + lane) * 4]; \
          Dv = ymfma(am, bfr, Dv); }

    #define PRED_BODY(T, BUF)                                                         \
        const int g0  = chmin / GRPSZ;                                                \
        const int g1  = (chmin + 1755) / GRPSZ;                                       \
        const int myg = (chmin + mybase) / GRPSZ;                                     \
        float4v Cb;                                                                   \
        _Pragma("unroll")                                                             \
        for (int rr = 0; rr < 4; ++rr) Cb[rr] = bp[chmin + rr * 576 + quad * 9];      \
        _Pragma("unroll")                                                             \
        for (int nt = 0; nt < 2; ++nt) {                                              \
            float4v Dv = Cb;                                                          \
            if (g0 == 0)      { PASS(0, nt) if (g1 == 1) PASS(1, nt) }                \
            else if (g0 == 1) { PASS(1, nt) if (g1 == 2) PASS(2, nt) }                \
            else if (g0 == 2) { PASS(2, nt) if (g1 == 3) PASS(3, nt) }                \
            else              { PASS(3, nt) }                                         \
            const int px = nt * 16 + lrow;                                            \
            if (px < NPX) {                                                           \
                unsigned short* p = &S[BUF][px * PXS2 + (c0 + quad) * 18 + uu * 4];   \
                *(unsigned int*)(p)     = pk2bf(Dv[0], Dv[1]);                        \
                *(unsigned int*)(p + 2) = pk2bf(Dv[2], Dv[3]);                        \
            }                                                                         \
        }

    // tap-0 PRED: inline loads (prologue, nothing to prefetch from)
    #define PRED_SLICE0(T, BUF)                                                       \
    _Pragma("unroll")                                                                 \
    for (int uu = 0; uu < 4; ++uu) {                                                  \
        const int chmin = uu * 2304 + c0 * 9 + (T);                                   \
        const int mych  = chmin + mybase;                                             \
        const short4v a = *(const short4v*)(Wb + (size_t)mych * 16 + quad * 4);       \
        PRED_BODY(T, BUF)                                                             \
    }

    // steady-state PRED with fused per-uu prefetch: consume apre[uu] for tap
    // T, immediately re-load it for tap TP=T+1 (register provably free),
    // THEN run the body -- each load gains up to 3 body-lengths of slack
    // over the R18 all-bodies-then-all-loads order.
    #define PRED_COMPUTE_PF(T, BUF, TP, DOPF)                                         \
    _Pragma("unroll")                                                                 \
    for (int uu = 0; uu < 4; ++uu) {                                                  \
        const int chmin = uu * 2304 + c0 * 9 + (T);                                   \
        const short4v a = apre[uu];                                                   \
        if (DOPF) {                                                                   \
            const int mychp = uu * 2304 + c0 * 9 + (TP) + mybase;                     \
            apre[uu] = *(const short4v*)(Wb + (size_t)mychp * 16 + quad * 4);         \
        }                                                                             \
        PRED_BODY(T, BUF)                                                             \
    }

    PRED_SLICE0(0, 0)
    PRED_PREFETCH(1)
    __syncthreads();   // covers Qs, dynb, S[0]

    // ---- Y-task assignment: 72 (px,Nt) tasks over 16 waves ----
    const int ntask  = (wave < 8) ? 5 : 4;
    const int tstart = (wave < 8) ? 5 * wave : 40 + 4 * (wave - 8);
    float acc[5] = {0.f, 0.f, 0.f, 0.f, 0.f};

    // ---- hoist tap-invariant Q fragments: one b64 load per task, ONCE ----
    short4v Bq[5];
    #pragma unroll
    for (int k = 0; k < 5; ++k) {
        if (k < ntask) {
            const int tau = tstart + k;
            const int px  = tau >> 2;
            const int Nt  = tau & 3;
            Bq[k] = *(const short4v*)&Qs[px * QS2 + (Nt * 16 + lrow) * 18 + quad * 4];
        } else {
            Bq[k] = (short4v)0;
        }
    }

    for (int t = 0; t < KK; ++t) {
        const int buf = t & 1;

        // ---- R18 order restored: PRED(t+1) + fused PREFETCH(t+2) first ----
        if (t < 8) { PRED_COMPUTE_PF(t + 1, (t + 1) & 1, t + 2, (t < 7)) }

        const int tr = t / 3, tc = t - 3 * (t / 3);

        int lastpx = -1;
        short4v Ap[4];                      // K=16 fragments: 2 VGPRs each
        float4v pv4[4];
        #pragma unroll
        for (int k = 0; k < 5; ++k) {
            if (k < ntask) {
                const int tau = tstart + k;
                const int px  = tau >> 2;
                const int pr = px / 6, pc = px - 6 * (px / 6);

                if (px != lastpx) {          // wave-uniform branch
                    lastpx = px;
                    #pragma unroll
                    for (int Mt = 0; Mt < 4; ++Mt)   // all 64 lanes load (k=quad*4+i)
                        Ap[Mt] = *(const short4v*)&S[buf][px * PXS2 + (Mt * 16 + lrow) * 18 + quad * 4];
                    const int spb = ((pr + tr) * 8 + pc + tc) * 64;
                    #pragma unroll
                    for (int Mt = 0; Mt < 4; ++Mt)
                        pv4[Mt] = *(const float4v*)&xtT[spb + Mt * 16 + quad * 4];
                }

                // packed f32x2 reduction (v_pk_fma_f32)
                float2v n2 = {0.f, 0.f}, d2 = {0.f, 0.f};
                #pragma unroll
                for (int Mt = 0; Mt < 4; ++Mt) {
                    float4v Dv = {0.f, 0.f, 0.f, 0.f};
                    Dv = ymfma(Ap[Mt], Bq[k], Dv);
                    const float2v y0 = {Dv[0], Dv[1]},        y1 = {Dv[2], Dv[3]};
                    const float2v p0 = {pv4[Mt][0], pv4[Mt][1]}, p1 = {pv4[Mt][2], pv4[Mt][3]};
                    n2 = y0 * y0 + n2;  n2 = y1 * y1 + n2;
                    d2 = p0 * y0 + d2;  d2 = p1 * y1 + d2;
                }
                float nacc  = n2[0] + n2[1];
                float dpacc = d2[0] + d2[1];
                nacc  += __shfl_xor(nacc, 16);  nacc  += __shfl_xor(nacc, 32);
                dpacc += __shfl_xor(dpacc, 16); dpacc += __shfl_xor(dpacc, 32);
                acc[k] += dpacc * rsqrtf(fmaxf(nacc, 1e-24f));
            }
        }
        __syncthreads();
    }

    // ---- write out ----
    if (quad == 0) {
        #pragma unroll
        for (int k = 0; k < 5; ++k) {
            if (k < ntask) {
                const int tau = tstart + k;
                const int px  = tau >> 2;
                const int Nt  = tau & 3;
                const int pr = px / 6, pc = px - 6 * (px / 6);
                const int l  = (h0 + pr) * WW + (w0 + pc);
                const int o  = Nt * 16 + lrow;
                out[((size_t)b * OUTC + o) * LPIX + l] = acc[k] + dynb[px * DBS + o];
            }
        }
    }
}

extern "C" void kernel_launch(void* const* d_in, const int* in_sizes, int n_in,
                              void* d_out, int out_size, void* d_ws, size_t ws_size,
                              hipStream_t stream) {
    const float* x  = (const float*)d_in[0];
    const float* Wp = (const float*)d_in[1];
    const float* bp = (const float*)d_in[2];
    float* out = (float*)d_out;
    unsigned short* Wb = (unsigned short*)d_ws;   // PREDCH*16 bf16 = 330 KB
    (void)in_sizes; (void)n_in; (void)out_size; (void)ws_size;

    hipLaunchKernelGGL(cvt_wp, dim3(160), dim3(256), 0, stream, Wp, Wb);
    hipLaunchKernelGGL(dppc27, dim3(BATCH * 128), dim3(1024), 0, stream, x, Wb, bp, out);
}

// Round 21
// 99.542 us; speedup vs baseline: 1.0872x; 1.0707x over previous
//
#include <hip/hip_runtime.h>
#include <math.h>

#if defined(__has_include)
#if __has_include(<hip/hip_bf16.h>)
#include <hip/hip_bf16.h>
#define HAVE_BF16_H 1
#endif
#endif

#define CIN    64
#define OUTC   64
#define BOT    16
#define KK     9
#define HH     48
#define WW     48
#define LPIX   (HH*WW)
#define WSZ    9216
#define PSZ    1024
#define PREDCH 10304
#define GRPSZ  2576
#define BATCH  2
#define NPX    18          // 3 rows x 6 cols of pixels per block
#define PXS2   1172        // px-stride (ushorts): 64*18 + 20 pad (conflict-free)
#define QS2    1160        // Q px-stride (ushorts): 64*18 + 8 pad
#define DBS    65

typedef __attribute__((ext_vector_type(8))) short short8v;
typedef __attribute__((ext_vector_type(4))) short short4v;
typedef __attribute__((ext_vector_type(4))) float float4v;
typedef __attribute__((ext_vector_type(2))) float float2v;

__device__ inline unsigned short f2bf(float f){
    unsigned u = __float_as_uint(f);
    return (unsigned short)((u + 0x7FFFu + ((u>>16)&1u)) >> 16);   // RNE
}

// Packed f32x2 -> bf16x2 (low = lo).  Native path lowers to
// v_cvt_pk_bf16_f32 (RNE, bit-identical to f2bf).  No inline asm (R6).
__device__ inline unsigned pk2bf(float lo, float hi){
#ifdef HAVE_BF16_H
    __hip_bfloat162 t = __float22bfloat162_rn(float2{lo, hi});
    unsigned r; __builtin_memcpy(&r, &t, 4); return r;
#else
    return (unsigned)f2bf(lo) | ((unsigned)f2bf(hi) << 16);
#endif
}

// K=16 bf16 MFMA (2-VGPR operands; lane: row=lane&15, k=quad*4+i).
// Verified numerically in R14-R18.  Fallback zero-extends to K=32.
#if __has_builtin(__builtin_amdgcn_mfma_f32_16x16x16bf16_1k)
__device__ __forceinline__ float4v ymfma(short4v a, short4v b, float4v c) {
    return __builtin_amdgcn_mfma_f32_16x16x16bf16_1k(a, b, c, 0, 0, 0);
}
#else
__device__ __forceinline__ float4v ymfma(short4v a, short4v b, float4v c) {
    short8v a8 = {a[0], a[1], a[2], a[3], 0, 0, 0, 0};
    short8v b8 = {b[0], b[1], b[2], b[3], 0, 0, 0, 0};
    return __builtin_amdgcn_mfma_f32_16x16x32_bf16(a8, b8, c, 0, 0, 0);
}
#endif

__global__ __launch_bounds__(256) void cvt_wp(const float* __restrict__ Wp,
                                              unsigned short* __restrict__ Wb) {
    const int n = PREDCH * 16;
    for (int i = blockIdx.x * 256 + threadIdx.x; i < n; i += gridDim.x * 256)
        Wb[i] = f2bf(Wp[i]);
}

// Block = 18 px (3x6), grid 256 (1/CU), 1024 threads (16 waves).
// BYTE-EXACT REVERT to dppc25 (R18, profiled 47.2us / wall 100.4us -- the
// session champion).  Both scheduling departures from it were measured and
// LOSE: R19 (Y-first) 55.2us -- starved PREFETCH of issue slack; R20
// (fused per-uu prefetch) 54.1us -- embedding the Wb load in PRED_BODY
// broke the compiler's schedule around the simple structure.  Consistent
// with the guide's m131-m141: hipcc's own schedule of the plain
// {PRED -> PREFETCH -> Y -> barrier} tap is near-optimal; source-level
// reorderings perturb it destructively.  All banked mechanisms: 16-wave
// single block, xtT transposed gather, PRED row-remap + packed b32 stores,
// rsqrt epilogue, apre[4] cross-tap prefetch, K=16 MFMA everywhere,
// pk2bf packed conversion, float2 packed reduction, bias via MFMA C,
// hoisted Bq, hard-coded PRED geometry.  Zero spill at VGPR 60.
__global__ __launch_bounds__(1024) __attribute__((amdgpu_waves_per_eu(4, 4)))
void dppc25r(
    const float* __restrict__ x,
    const unsigned short* __restrict__ Wb,
    const float* __restrict__ bp,
    float* __restrict__ out)
{
    __shared__ float          xt[64 * 5 * 8];       // 10240 B  [c][r5][c8]
    __shared__ float          xtT[5 * 8 * 64];      // 10240 B  [r5*8+c8][c]
    __shared__ unsigned short S[2][NPX * PXS2];     // 84384 B  P_t dbuf
    __shared__ unsigned short Qs[NPX * QS2];        // 41760 B  Q [px][o*18+d]
    __shared__ unsigned short Bfs[4 * 2 * 64 * 4];  //  4096 B  pred B-frags [g][nt][lane][4]
    __shared__ float          dynb[NPX * DBS];      //  4680 B

    const int tid  = threadIdx.x;
    const int wave = tid >> 6;
    const int lane = tid & 63;
    const int quad = lane >> 4;
    const int lrow = lane & 15;

    const int bi = blockIdx.x;
    const int b  = bi >> 7;
    const int r  = bi & 127;
    const int h0 = (r >> 3) * 3;
    const int w0 = (r & 7) * 6;

    // ---- xt load (coalesced global) ----
    const float* xb = x + (size_t)b * CIN * LPIX;
    for (int i = tid; i < 64 * 5 * 8; i += 1024) {
        const int c  = i / 40;
        const int rm = i - c * 40;
        const int hi = h0 - 1 + (rm >> 3);
        const int wi = w0 - 1 + (rm & 7);
        float v = 0.0f;
        if (hi >= 0 && hi < HH && wi >= 0 && wi < WW)
            v = xb[c * LPIX + hi * WW + wi];
        xt[i] = v;
    }
    __syncthreads();

    // ---- waves 0-7: pred B-frags -> LDS (K=16 layout: c = g*16+quad*4+i) ----
    if (wave < 8) {
        const int g  = wave >> 1;
        const int nt = wave & 1;
        const int px = nt * 16 + lrow;
        unsigned fw[2] = {0u, 0u};
        if (px < NPX) {
            const int pr = px / 6, pc = px - 6 * (px / 6);
            #pragma unroll
            for (int jj = 0; jj < 2; ++jj) {
                const float x0 = xt[((g * 16 + quad * 4 + 2 * jj)     * 5 + pr + 1) * 8 + pc + 1];
                const float x1 = xt[((g * 16 + quad * 4 + 2 * jj + 1) * 5 + pr + 1) * 8 + pc + 1];
                fw[jj] = pk2bf(x0, x1);
            }
        }
        unsigned* bq = (unsigned*)&Bfs[((g * 2 + nt) * 64 + lane) * 4];
        bq[0] = fw[0]; bq[1] = fw[1];
    } else {
        // ---- waves 8-15: transpose xt -> xtT[spatial][c] (for pv b128 reads) ----
        for (int i = tid - 512; i < 64 * 5 * 8; i += 512) {
            const int sp = i >> 6;
            const int c  = i & 63;
            xtT[i] = xt[c * 40 + sp];
        }
    }
    __syncthreads();

    // ---- Q + dyn_b phase (group 3), K=16, bias via C operand ----
    for (int u = wave; u < 68; u += 16) {
        const int ch0  = WSZ + u * 16;
        const int mych = ch0 + lrow;
        const short4v a = *(const short4v*)(Wb + (size_t)mych * 16 + quad * 4);
        float4v Cb;
        #pragma unroll
        for (int rr = 0; rr < 4; ++rr) Cb[rr] = bp[ch0 + quad * 4 + rr];
        #pragma unroll
        for (int nt = 0; nt < 2; ++nt) {
            const short4v bfr = *(const short4v*)&Bfs[((3 * 2 + nt) * 64 + lane) * 4];
            const float4v Dv = ymfma(a, bfr, Cb);
            const int px = nt * 16 + lrow;
            if (px < NPX) {
                if (u < 64) {   // proj region: 4 consecutive ushorts, packed b32
                    unsigned short* p = &Qs[px * QS2 + u * 18 + quad * 4];
                    *(unsigned int*)(p)     = pk2bf(Dv[0], Dv[1]);
                    *(unsigned int*)(p + 2) = pk2bf(Dv[2], Dv[3]);
                } else {        // dyn_b region
                    #pragma unroll
                    for (int rr = 0; rr < 4; ++rr)
                        dynb[px * DBS + (u - 64) * 16 + quad * 4 + rr] = Dv[rr];
                }
            }
        }
    }

    // ---- PRED geometry (u&15 == wave): c0 = 4*wave invariant; d0 = 4*uu ----
    const int c0    = wave * 4;
    const int mybase = (lrow & 3) * 576 + (lrow >> 2) * 9;   // row-remap offset

    // ---- cross-tap A-fragment prefetch: FULL depth, K=16 (8 VGPRs) ----
    short4v apre[4];

    #define PRED_PREFETCH(T)                                                          \
    _Pragma("unroll")                                                                 \
    for (int uu = 0; uu < 4; ++uu) {                                                  \
        const int mych = uu * 2304 + c0 * 9 + (T) + mybase;                           \
        apre[uu] = *(const short4v*)(Wb + (size_t)mych * 16 + quad * 4);              \
    }

    // ---- pred slice for tap t into buf (K=16 MFMA, bias via C) ----
    // Row remap: A-row lrow -> channel chmin + (lrow&3)*576 + (lrow>>2)*9,
    // so Dv[rr] = (d=d0+rr, c=c0+quad); bias channel = chmin + rr*576 + quad*9.
    #define PASS(GG, NT)                                                              \
        { short4v am = (myg == (GG)) ? a : (short4v)0;                                \
          const short4v bfr = *(const short4v*)&Bfs[(((GG) * 2 + (NT)) * 64 + lane) * 4]; \
          Dv = ymfma(am, bfr, Dv); }

    #define PRED_BODY(T, BUF)                                                         \
        const int g0  = chmin / GRPSZ;                                                \
        const int g1  = (chmin + 1755) / GRPSZ;                                       \
        const int myg = (chmin + mybase) / GRPSZ;                                     \
        float4v Cb;                                                                   \
        _Pragma("unroll")                                                             \
        for (int rr = 0; rr < 4; ++rr) Cb[rr] = bp[chmin + rr * 576 + quad * 9];      \
        _Pragma("unroll")                                                             \
        for (int nt = 0; nt < 2; ++nt) {                                              \
            float4v Dv = Cb;                                                          \
            if (g0 == 0)      { PASS(0, nt) if (g1 == 1) PASS(1, nt) }                \
            else if (g0 == 1) { PASS(1, nt) if (g1 == 2) PASS(2, nt) }                \
            else if (g0 == 2) { PASS(2, nt) if (g1 == 3) PASS(3, nt) }                \
            else              { PASS(3, nt) }                                         \
            const int px = nt * 16 + lrow;                                            \
            if (px < NPX) {                                                           \
                unsigned short* p = &S[BUF][px * PXS2 + (c0 + quad) * 18 + uu * 4];   \
                *(unsigned int*)(p)     = pk2bf(Dv[0], Dv[1]);                        \
                *(unsigned int*)(p + 2) = pk2bf(Dv[2], Dv[3]);                        \
            }                                                                         \
        }

    // tap-0 PRED: inline loads (prologue, nothing to prefetch from)
    #define PRED_SLICE0(T, BUF)                                                       \
    _Pragma("unroll")                                                                 \
    for (int uu = 0; uu < 4; ++uu) {                                                  \
        const int chmin = uu * 2304 + c0 * 9 + (T);                                   \
        const int mych  = chmin + mybase;                                             \
        const short4v a = *(const short4v*)(Wb + (size_t)mych * 16 + quad * 4);       \
        PRED_BODY(T, BUF)                                                             \
    }

    // steady-state PRED: all 4 uu consume apre (prefetched one tap earlier)
    #define PRED_COMPUTE(T, BUF)                                                      \
    _Pragma("unroll")                                                                 \
    for (int uu = 0; uu < 4; ++uu) {                                                  \
        const int chmin = uu * 2304 + c0 * 9 + (T);                                   \
        const short4v a = apre[uu];                                                   \
        PRED_BODY(T, BUF)                                                             \
    }

    PRED_SLICE0(0, 0)
    PRED_PREFETCH(1)
    __syncthreads();   // covers Qs, dynb, S[0]

    // ---- Y-task assignment: 72 (px,Nt) tasks over 16 waves ----
    const int ntask  = (wave < 8) ? 5 : 4;
    const int tstart = (wave < 8) ? 5 * wave : 40 + 4 * (wave - 8);
    float acc[5] = {0.f, 0.f, 0.f, 0.f, 0.f};

    // ---- hoist tap-invariant Q fragments: one b64 load per task, ONCE ----
    short4v Bq[5];
    #pragma unroll
    for (int k = 0; k < 5; ++k) {
        if (k < ntask) {
            const int tau = tstart + k;
            const int px  = tau >> 2;
            const int Nt  = tau & 3;
            Bq[k] = *(const short4v*)&Qs[px * QS2 + (Nt * 16 + lrow) * 18 + quad * 4];
        } else {
            Bq[k] = (short4v)0;
        }
    }

    for (int t = 0; t < KK; ++t) {
        const int buf = t & 1;
        if (t < 8) { PRED_COMPUTE(t + 1, (t + 1) & 1) }
        if (t < 7) { PRED_PREFETCH(t + 2) }

        const int tr = t / 3, tc = t - 3 * (t / 3);

        int lastpx = -1;
        short4v Ap[4];                      // K=16 fragments: 2 VGPRs each
        float4v pv4[4];
        #pragma unroll
        for (int k = 0; k < 5; ++k) {
            if (k < ntask) {
                const int tau = tstart + k;
                const int px  = tau >> 2;
                const int pr = px / 6, pc = px - 6 * (px / 6);

                if (px != lastpx) {          // wave-uniform branch
                    lastpx = px;
                    #pragma unroll
                    for (int Mt = 0; Mt < 4; ++Mt)   // all 64 lanes load (k=quad*4+i)
                        Ap[Mt] = *(const short4v*)&S[buf][px * PXS2 + (Mt * 16 + lrow) * 18 + quad * 4];
                    const int spb = ((pr + tr) * 8 + pc + tc) * 64;
                    #pragma unroll
                    for (int Mt = 0; Mt < 4; ++Mt)
                        pv4[Mt] = *(const float4v*)&xtT[spb + Mt * 16 + quad * 4];
                }

                // packed f32x2 reduction (v_pk_fma_f32)
                float2v n2 = {0.f, 0.f}, d2 = {0.f, 0.f};
                #pragma unroll
                for (int Mt = 0; Mt < 4; ++Mt) {
                    float4v Dv = {0.f, 0.f, 0.f, 0.f};
                    Dv = ymfma(Ap[Mt], Bq[k], Dv);
                    const float2v y0 = {Dv[0], Dv[1]},        y1 = {Dv[2], Dv[3]};
                    const float2v p0 = {pv4[Mt][0], pv4[Mt][1]}, p1 = {pv4[Mt][2], pv4[Mt][3]};
                    n2 = y0 * y0 + n2;  n2 = y1 * y1 + n2;
                    d2 = p0 * y0 + d2;  d2 = p1 * y1 + d2;
                }
                float nacc  = n2[0] + n2[1];
                float dpacc = d2[0] + d2[1];
                nacc  += __shfl_xor(nacc, 16);  nacc  += __shfl_xor(nacc, 32);
                dpacc += __shfl_xor(dpacc, 16); dpacc += __shfl_xor(dpacc, 32);
                acc[k] += dpacc * rsqrtf(fmaxf(nacc, 1e-24f));
            }
        }
        __syncthreads();
    }

    // ---- write out ----
    if (quad == 0) {
        #pragma unroll
        for (int k = 0; k < 5; ++k) {
            if (k < ntask) {
                const int tau = tstart + k;
                const int px  = tau >> 2;
                const int Nt  = tau & 3;
                const int pr = px / 6, pc = px - 6 * (px / 6);
                const int l  = (h0 + pr) * WW + (w0 + pc);
                const int o  = Nt * 16 + lrow;
                out[((size_t)b * OUTC + o) * LPIX + l] = acc[k] + dynb[px * DBS + o];
            }
        }
    }
}

extern "C" void kernel_launch(void* const* d_in, const int* in_sizes, int n_in,
                              void* d_out, int out_size, void* d_ws, size_t ws_size,
                              hipStream_t stream) {
    const float* x  = (const float*)d_in[0];
    const float* Wp = (const float*)d_in[1];
    const float* bp = (const float*)d_in[2];
    float* out = (float*)d_out;
    unsigned short* Wb = (unsigned short*)d_ws;   // PREDCH*16 bf16 = 330 KB
    (void)in_sizes; (void)n_in; (void)out_size; (void)ws_size;

    hipLaunchKernelGGL(cvt_wp, dim3(160), dim3(256), 0, stream, Wp, Wb);
    hipLaunchKernelGGL(dppc25r, dim3(BATCH * 128), dim3(1024), 0, stream, x, Wb, bp, out);
}